// Round 17
// baseline (45.661 us; speedup 1.0000x reference)
//
#include <hip/hip_runtime.h>
#include <cstdint>

#define B_ 2048
#define T_ 2048
#define TD 7
#define IDENT 0x4688u    // identity 3-bit map

__device__ __forceinline__ uint32_t mcompose(uint32_t f, uint32_t g) {
    uint32_t r = 0;
#pragma unroll
    for (int j = 0; j < 5; ++j) {
        uint32_t gj = (g >> (3 * j)) & 7u;
        r |= ((f >> (3 * gj)) & 7u) << (3 * j);
    }
    return r;
}

__device__ __forceinline__ uint32_t cvtpk(float lo, float hi) {
    uint32_t r;
    asm("v_cvt_pk_bf16_f32 %0, %1, %2" : "=v"(r) : "v"(lo), "v"(hi));
    return r;
}
__device__ __forceinline__ float blo(uint32_t w) { return __uint_as_float(w << 16); }
__device__ __forceinline__ float bhi(uint32_t w) { return __uint_as_float(w & 0xFFFF0000u); }

__device__ __forceinline__ void hstep5(float x0, float x1, float x2, float x3, float x4,
                                       bool mm, float (&dp)[5], const float (&tr)[5][5]) {
    const float xx[5] = {x0, x1, x2, x3, x4};
    float nd[5];
#pragma unroll
    for (int j = 0; j < 5; ++j) {
        float v = fmaxf(fmaxf(fmaxf(fmaxf(dp[0] + tr[0][j], dp[1] + tr[1][j]),
                                    dp[2] + tr[2][j]), dp[3] + tr[3][j]),
                        dp[4] + tr[4][j]);
        nd[j] = v + xx[j];
    }
#pragma unroll
    for (int j = 0; j < 5; ++j) dp[j] = mm ? nd[j] : dp[j];
}

__device__ __forceinline__ uint32_t vstep5(float x0, float x1, float x2, float x3, float x4,
                                           bool mm, float (&dp)[5], const float (&tr)[5][5]) {
    const float xx[5] = {x0, x1, x2, x3, x4};
    float nd[5]; uint32_t pk = 0;
#pragma unroll
    for (int j = 0; j < 5; ++j) {
        float s[5];
#pragma unroll
        for (int i = 0; i < 5; ++i) {
            float f = dp[i] + tr[i][j];
            s[i] = __uint_as_float((__float_as_uint(f) & ~7u) | (uint32_t)(7 - i));
        }
        float m = fmaxf(fmaxf(fmaxf(fmaxf(s[0], s[1]), s[2]), s[3]), s[4]);
        int a = 7 - (int)(__float_as_uint(m) & 7u);
        float v = m + xx[j];
        a = mm ? a : j;
        nd[j] = mm ? v : dp[j];
        pk |= ((uint32_t)a) << (3 * j);
    }
#pragma unroll
    for (int j = 0; j < 5; ++j) dp[j] = nd[j];
    return pk;
}

// bf16-pack float4 of f4-index (c + 64q) into XOR-swizzled LDS
__device__ __forceinline__ void stage_write(uint32_t* __restrict__ xs32, int c, int q,
                                            const float4& v) {
    uint32_t e0 = 4u * (uint32_t)(c + 64 * q);
    uint32_t co = e0 / 160u;                 // exact (compiler magic)
    uint32_t k  = (e0 - 160u * co) >> 1;
    uint32_t sw = (co >> 1) & 15u;
    xs32[80u * co + (k ^ sw)]        = cvtpk(v.x, v.y);
    xs32[80u * co + ((k + 1u) ^ sw)] = cvtpk(v.z, v.w);
}

__device__ __forceinline__ uint32_t mask_bits8(const int4 (&m)[8]) {
    uint32_t mb = 0;
#pragma unroll
    for (int u = 0; u < 8; ++u) {
        mb |= (m[u].x ? 1u : 0u) << (4 * u);
        mb |= (m[u].y ? 1u : 0u) << (4 * u + 1);
        mb |= (m[u].z ? 1u : 0u) << (4 * u + 2);
        mb |= (m[u].w ? 1u : 0u) << (4 * u + 3);
    }
    return mb;
}

// full per-row pipeline; if PR, interleave bf16 staging of pf -> xsB
template<bool PR>
__device__ __forceinline__ void compute_row(
    const uint32_t* __restrict__ xs32, uint32_t* __restrict__ xsB,
    const float4 (&pf)[40], uint32_t mb, int b, int c,
    const float (&tr)[5][5], const float (&ts)[5], const float (&te)[5],
    float* __restrict__ out)
{
    uint32_t mh = __shfl_up(mb, 1);
    mh = (c > 0) ? (mh >> 16) : 0u;
    if (c == 0) mb &= ~1u;               // t==0 slot: identity (dp preset exactly)

    const int hc = (c > 0) ? c - 1 : 0;
    const uint32_t swl = (uint32_t)((c >> 1) & 15);
    const uint32_t swh = (uint32_t)((hc >> 1) & 15);
    const uint32_t* xl = xs32 + 80 * c;
    const uint32_t* xh = xs32 + 80 * hc;

    // halo init + 15 warm-up steps (prev chunk steps 16..31)
    float dp[5];
    {
        uint32_t w0 = xh[40u ^ swh], w1 = xh[41u ^ swh], w2 = xh[42u ^ swh];
        dp[0] = blo(w0); dp[1] = bhi(w0); dp[2] = blo(w1); dp[3] = bhi(w1); dp[4] = blo(w2);
    }
    for (int hi = 0; hi < 7; ++hi) {
        uint32_t d0 = (uint32_t)(42 + 5 * hi);
        uint32_t w0 = xh[(d0 + 0u) ^ swh], w1 = xh[(d0 + 1u) ^ swh], w2 = xh[(d0 + 2u) ^ swh];
        uint32_t w3 = xh[(d0 + 3u) ^ swh], w4 = xh[(d0 + 4u) ^ swh], w5 = xh[(d0 + 5u) ^ swh];
        bool m1 = ((mh >> (2 * hi + 1)) & 1u) != 0;
        bool m2 = ((mh >> (2 * hi + 2)) & 1u) != 0;
        hstep5(bhi(w0), blo(w1), bhi(w1), blo(w2), bhi(w2), m1, dp, tr);
        hstep5(blo(w3), bhi(w3), blo(w4), bhi(w4), blo(w5), m2, dp, tr);
    }
    {
        uint32_t w0 = xh[77u ^ swh], w1 = xh[78u ^ swh], w2 = xh[79u ^ swh];
        bool m1 = ((mh >> 15) & 1u) != 0;
        hstep5(bhi(w0), blo(w1), bhi(w1), blo(w2), bhi(w2), m1, dp, tr);
    }
    if (c == 0) {                        // exact t==0 init (chunk 0 swizzle = 0)
        uint32_t w0 = xs32[0], w1 = xs32[1], w2 = xs32[2];
        dp[0] = blo(w0) + ts[0]; dp[1] = bhi(w0) + ts[1];
        dp[2] = blo(w1) + ts[2]; dp[3] = bhi(w1) + ts[3];
        dp[4] = blo(w2) + ts[4];
    }
    float dpE[5];
#pragma unroll
    for (int j = 0; j < 5; ++j) dpE[j] = (c == 0) ? 0.0f : dp[j];

    if constexpr (PR) {                  // prefetch-write group 0 (loads covered by halo)
#pragma unroll
        for (int q = 0; q < 10; ++q) stage_write(xsB, c, q, pf[q]);
    }

    // live: 16 unrolled iters x 2 steps, bp in registers
    uint32_t acc[16];
    uint32_t rho = IDENT;
#pragma unroll
    for (int it = 0; it < 16; ++it) {
        uint32_t d0 = (uint32_t)(5 * it);
        uint32_t w0 = xl[(d0 + 0u) ^ swl], w1 = xl[(d0 + 1u) ^ swl], w2 = xl[(d0 + 2u) ^ swl];
        uint32_t w3 = xl[(d0 + 3u) ^ swl], w4 = xl[(d0 + 4u) ^ swl];
        bool mA = ((mb >> (2 * it)) & 1u) != 0;
        bool mB = ((mb >> (2 * it + 1)) & 1u) != 0;
        uint32_t pkA = vstep5(blo(w0), bhi(w0), blo(w1), bhi(w1), blo(w2), mA, dp, tr);
        rho = mcompose(rho, pkA);
        uint32_t pkB = vstep5(bhi(w2), blo(w3), bhi(w3), blo(w4), bhi(w4), mB, dp, tr);
        rho = mcompose(rho, pkB);
        acc[it] = pkA | (pkB << 16);
        if constexpr (PR) {
            if (it == 4) {
#pragma unroll
                for (int q = 10; q < 20; ++q) stage_write(xsB, c, q, pf[q]);
            }
            if (it == 9) {
#pragma unroll
                for (int q = 20; q < 30; ++q) stage_write(xsB, c, q, pf[q]);
            }
            if (it == 14) {
#pragma unroll
                for (int q = 30; q < 40; ++q) stage_write(xsB, c, q, pf[q]);
            }
        }
    }

    // exact per-chunk segment score (within-lane telescoping)
    float svec[5];
#pragma unroll
    for (int j = 0; j < 5; ++j) {
        int r = (rho >> (3 * j)) & 7;
        float e = dpE[0];
        e = (r == 1) ? dpE[1] : e;
        e = (r == 2) ? dpE[2] : e;
        e = (r == 3) ? dpE[3] : e;
        e = (r == 4) ? dpE[4] : e;
        svec[j] = dp[j] - e;
    }

    // wave suffix composition over 64 chunks
    uint32_t I = rho;
#pragma unroll
    for (int d = 1; d < 64; d <<= 1) {
        uint32_t oth = __shfl_down(I, d);
        uint32_t cm  = mcompose(I, oth);
        I = (c + d < 64) ? cm : I;
    }
    float best = dp[0] + te[0]; int lastv = 0;
#pragma unroll
    for (int j = 1; j < 5; ++j) {
        float s = dp[j] + te[j];
        if (s > best) { best = s; lastv = j; }
    }
    const int last = __shfl(lastv, 63);
    uint32_t M = __shfl_down(I, 1);
    M = (c < 63) ? M : IDENT;
    const int ec = (int)((M >> (3 * last)) & 7u);

    // exact telescoped score: wave reduce
    {
        float v = svec[0];
        v = (ec == 1) ? svec[1] : v;
        v = (ec == 2) ? svec[2] : v;
        v = (ec == 3) ? svec[3] : v;
        v = (ec == 4) ? svec[4] : v;
        if (c == 63) v += te[last];
#pragma unroll
        for (int off = 1; off < 64; off <<= 1) v += __shfl_xor(v, off);
        if (c == 0) out[b] = v;
    }

    // path decode from register bp
    float pv[32];
    int e = ec;
#pragma unroll
    for (int l = 31; l >= 0; --l) {
        pv[l] = (float)e;
        uint32_t p = (acc[l >> 1] >> (16 * (l & 1))) & 0xFFFFu;
        e = (p >> (3 * e)) & 7;
    }
    float* path = out + B_ + (size_t)b * T_ + 32 * c;
#pragma unroll
    for (int q = 0; q < 8; ++q) {
        float4 v; v.x = pv[4*q]; v.y = pv[4*q+1]; v.z = pv[4*q+2]; v.w = pv[4*q+3];
        ((float4*)path)[q] = v;
    }
}

__global__ __launch_bounds__(64, 1) void k_all(
    const float* __restrict__ x, const int* __restrict__ mask,
    const float* __restrict__ tf, float* __restrict__ out)
{
    __shared__ __align__(16) uint32_t xsA[5120];   // 20480 B
    __shared__ __align__(16) uint32_t xsB[5120];   // 20480 B  (2 bufs -> 4 blocks/CU)
    const int c = threadIdx.x;
    const int b0 = 2 * blockIdx.x, b1 = b0 + 1;

    const float4* gx0 = (const float4*)(x + (size_t)b0 * (T_ * 5));
    const float4* gx1 = (const float4*)(x + (size_t)b1 * (T_ * 5));
    const int4*   gm0 = (const int4*)(mask + (size_t)b0 * T_ + 32 * c);
    const int4*   gm1 = (const int4*)(mask + (size_t)b1 * T_ + 32 * c);

    // ---- stage row0 (exposed) ----
#pragma unroll
    for (int qo = 0; qo < 5; ++qo) {
        float4 v[8];
#pragma unroll
        for (int u = 0; u < 8; ++u) v[u] = gx0[c + 64 * (8 * qo + u)];
#pragma unroll
        for (int u = 0; u < 8; ++u) stage_write(xsA, c, 8 * qo + u, v[u]);
    }
    int4 m0[8];
#pragma unroll
    for (int u = 0; u < 8; ++u) m0[u] = gm0[u];
    const uint32_t mb0 = mask_bits8(m0);

    float tr[5][5], ts[5], te[5];
#pragma unroll
    for (int i = 0; i < 5; ++i)
#pragma unroll
        for (int j = 0; j < 5; ++j) tr[i][j] = tf[i * TD + j];
#pragma unroll
    for (int j = 0; j < 5; ++j) ts[j] = tf[5 * TD + j];
#pragma unroll
    for (int j = 0; j < 5; ++j) te[j] = tf[j * TD + 6];

    __syncthreads();

    // ---- issue row1 loads; held in registers across row0 compute ----
    float4 pf[40];
#pragma unroll
    for (int q = 0; q < 40; ++q) pf[q] = gx1[c + 64 * q];
    int4 m1[8];
#pragma unroll
    for (int u = 0; u < 8; ++u) m1[u] = gm1[u];
    __builtin_amdgcn_sched_barrier(0);

    // ---- compute row0, staging row1 into xsB along the way ----
    compute_row<true>(xsA, xsB, pf, mb0, b0, c, tr, ts, te, out);

    const uint32_t mb1 = mask_bits8(m1);
    __syncthreads();

    // ---- compute row1 (stage fully hidden) ----
    compute_row<false>(xsB, xsA, pf, mb1, b1, c, tr, ts, te, out);
}

extern "C" void kernel_launch(void* const* d_in, const int* in_sizes, int n_in,
                              void* d_out, int out_size, void* d_ws, size_t ws_size,
                              hipStream_t stream) {
    const float* x         = (const float*)d_in[0];
    const int*   mask      = (const int*)d_in[1];
    const float* transform = (const float*)d_in[2];
    float*       out       = (float*)d_out;

    hipLaunchKernelGGL(k_all, dim3(B_ / 2), dim3(64), 0, stream,
                       x, mask, transform, out);
}

// Round 18
// 36.480 us; speedup vs baseline: 1.2517x; 1.2517x over previous
//
#include <hip/hip_runtime.h>
#include <cstdint>

#define B_    2048
#define T_    2048
#define TD    7
#define IDENT 0x4688u    // identity map: 0|1<<3|2<<6|3<<9|4<<12

// compose packed 5-slot maps: r[j] = f[g[j]]
__device__ __forceinline__ uint32_t mcompose(uint32_t f, uint32_t g) {
    uint32_t r = 0;
#pragma unroll
    for (int j = 0; j < 5; ++j) {
        uint32_t gj = (g >> (3 * j)) & 7u;
        r |= ((f >> (3 * gj)) & 7u) << (3 * j);
    }
    return r;
}

// pack two f32 -> bf16 pair (RNE), low half = first arg
__device__ __forceinline__ uint32_t cvtpk(float lo, float hi) {
    uint32_t r;
    asm("v_cvt_pk_bf16_f32 %0, %1, %2" : "=v"(r) : "v"(lo), "v"(hi));
    return r;
}

// extract bf16 halfword h from packed dword window (h compile-time after unroll)
__device__ __forceinline__ float xget(const uint32_t* w, int h) {
    return (h & 1) ? __uint_as_float(w[h >> 1] & 0xFFFF0000u)
                   : __uint_as_float(w[h >> 1] << 16);
}

// uint4 index of logical group q (0..19) of chunk cc, with per-chunk rotation
// slot=(q+(cc&7))%20 -> 8 consecutive lanes hit 8 distinct bank quads
__device__ __forceinline__ int gidx(int cc, int q) {
    int s = q + (cc & 7);
    s = (s >= 20) ? s - 20 : s;
    return 20 * cc + s;
}

template<bool P>
__device__ __forceinline__ void hstep(const uint32_t* w, int base, bool pred,
                                      float (&dp)[5], const float (&tr)[5][5]) {
    float nd[5];
#pragma unroll
    for (int j = 0; j < 5; ++j) {
        float v = fmaxf(fmaxf(fmaxf(fmaxf(dp[0] + tr[0][j], dp[1] + tr[1][j]),
                                    dp[2] + tr[2][j]), dp[3] + tr[3][j]),
                        dp[4] + tr[4][j]);
        nd[j] = v + xget(w, base + j);
    }
#pragma unroll
    for (int j = 0; j < 5; ++j) dp[j] = (P && !pred) ? dp[j] : nd[j];
}

template<bool SEL>
__device__ __forceinline__ uint32_t lstep(const uint32_t* w, int base, bool mm,
                                          float (&dp)[5], const float (&tr)[5][5],
                                          uint32_t& rho) {
    float nd[5]; int aa[5]; uint32_t pk = 0;
#pragma unroll
    for (int j = 0; j < 5; ++j) {
        float s[5];
#pragma unroll
        for (int i = 0; i < 5; ++i) {
            float f = dp[i] + tr[i][j];
            s[i] = __uint_as_float((__float_as_uint(f) & ~7u) | (uint32_t)(7 - i));
        }
        float m = fmaxf(fmaxf(fmaxf(fmaxf(s[0], s[1]), s[2]), s[3]), s[4]); // 2x v_max3
        int a = 7 - (int)(__float_as_uint(m) & 7u);
        float v = m + xget(w, base + j);
        if (SEL) { a = mm ? a : j; nd[j] = mm ? v : dp[j]; }
        else     { nd[j] = v; }
        aa[j] = a;
        pk |= ((uint32_t)a) << (3 * j);
    }
    uint32_t nr = 0;
#pragma unroll
    for (int j = 0; j < 5; ++j) nr |= ((rho >> (3 * aa[j])) & 7u) << (3 * j);
    rho = nr;
#pragma unroll
    for (int j = 0; j < 5; ++j) dp[j] = nd[j];
    return pk;
}

__global__ __launch_bounds__(64) void k_all(
    const float* __restrict__ x, const int* __restrict__ mask,
    const float* __restrict__ tf, float* __restrict__ out)
{
    __shared__ __align__(16) uint16_t xs[10240];   // 20480 B EXACT -> 8 blocks/CU
    const int b = blockIdx.x, c = threadIdx.x;     // c = chunk (L=32), 64 chunks

    const float4* gx = (const float4*)(x + (size_t)b * (T_ * 5));
    const int*    gi = mask + (size_t)b * T_;

    // ---- stage x: 40 coalesced float4/thread -> bf16 pairs, rotated groups ----
#pragma unroll
    for (int qi = 0; qi < 40; ++qi) {
        int fi = c + 64 * qi;
        float4 v = gx[fi];
        uint32_t e0 = 4u * (uint32_t)fi;
        uint32_t co = e0 / 160u;                 // owning chunk (exact)
        uint32_t el = e0 - 160u * co;            // element within chunk
        uint32_t q  = el >> 3;                   // logical group
        uint32_t s  = q + (co & 7u); s = (s >= 20u) ? s - 20u : s;
        uint32_t ha = 160u * co + 8u * s + (el & 7u);
        uint2 p; p.x = cvtpk(v.x, v.y); p.y = cvtpk(v.z, v.w);
        *(uint2*)(xs + ha) = p;
    }

    // ---- mask: coalesced dword loads + ballot pack (32 bits per chunk) ----
    uint32_t mb = 0;
    {
        int mv[32];
#pragma unroll
        for (int q = 0; q < 32; ++q) mv[q] = gi[c + 64 * q];
#pragma unroll
        for (int q = 0; q < 32; ++q) {
            unsigned long long bal = __ballot(mv[q] != 0);
            if (c == 2 * q)     mb = (uint32_t)bal;
            if (c == 2 * q + 1) mb = (uint32_t)(bal >> 32);
        }
    }

    float tr[5][5], ts[5], te[5];
#pragma unroll
    for (int i = 0; i < 5; ++i)
#pragma unroll
        for (int j = 0; j < 5; ++j) tr[i][j] = tf[i * TD + j];
#pragma unroll
    for (int j = 0; j < 5; ++j) ts[j] = tf[5 * TD + j];
#pragma unroll
    for (int j = 0; j < 5; ++j) te[j] = tf[j * TD + 6];

    const bool allm = __all(mb == 0xFFFFFFFFu);
    uint32_t mh = __shfl_up(mb, 1);
    mh = (c > 0) ? (mh >> 24) : 0u;              // halo bits = prev chunk steps 24..31

    __syncthreads();                             // xs staged

    const uint4* xsv = (const uint4*)xs;
    const int hc = (c > 0) ? c - 1 : 0;

    // ---- halo H=8: prev chunk groups 15..19 (steps 24..31), 7 warm-up steps ----
    uint32_t hw[20];
#pragma unroll
    for (int k = 0; k < 5; ++k) {
        uint4 t = xsv[gidx(hc, 15 + k)];
        hw[4*k] = t.x; hw[4*k+1] = t.y; hw[4*k+2] = t.z; hw[4*k+3] = t.w;
    }
    float dp[5];
#pragma unroll
    for (int j = 0; j < 5; ++j) dp[j] = xget(hw, j);   // raw init at step 32c-8 (approx)
    if (allm) {
#pragma unroll
        for (int h = 1; h <= 7; ++h) hstep<false>(hw, 5 * h, true, dp, tr);
    } else {
#pragma unroll
        for (int h = 1; h <= 7; ++h) hstep<true>(hw, 5 * h, ((mh >> h) & 1u) != 0, dp, tr);
    }
    if (c == 0) {                                // exact t=0 init (live l=0 masked)
        uint4 t0 = xsv[gidx(0, 0)];
        uint32_t w0[4] = { t0.x, t0.y, t0.z, t0.w };
#pragma unroll
        for (int j = 0; j < 5; ++j) dp[j] = xget(w0, j) + ts[j];
    }
    float dpE[5];
#pragma unroll
    for (int j = 0; j < 5; ++j) dpE[j] = (c == 0) ? 0.0f : dp[j];

    // ---- live: 32 exact steps, bp in registers, per-8-step group batches ----
    uint32_t acc[16];
    uint32_t rho = IDENT;
#pragma unroll
    for (int bb = 0; bb < 4; ++bb) {
        uint32_t w[20];
#pragma unroll
        for (int k = 0; k < 5; ++k) {
            uint4 t = xsv[gidx(c, 5 * bb + k)];
            w[4*k] = t.x; w[4*k+1] = t.y; w[4*k+2] = t.z; w[4*k+3] = t.w;
        }
#pragma unroll
        for (int ll = 0; ll < 8; ++ll) {
            const int l = 8 * bb + ll;
            uint32_t pk;
            if (l == 0) {
                bool mm = (c != 0) && ((mb & 1u) != 0);
                pk = lstep<true>(w, 0, mm, dp, tr, rho);
            } else if (allm) {
                pk = lstep<false>(w, 5 * ll, true, dp, tr, rho);
            } else {
                pk = lstep<true>(w, 5 * ll, ((mb >> l) & 1u) != 0, dp, tr, rho);
            }
            if (l & 1) acc[l >> 1] |= pk << 16;
            else       acc[l >> 1]  = pk;
        }
    }

    // exact per-chunk segment score of decoded tree (within-lane telescoping)
    float svec[5];
#pragma unroll
    for (int j = 0; j < 5; ++j) {
        int r = (rho >> (3 * j)) & 7;
        float e = dpE[0];
        e = (r == 1) ? dpE[1] : e;
        e = (r == 2) ? dpE[2] : e;
        e = (r == 3) ? dpE[3] : e;
        e = (r == 4) ? dpE[4] : e;
        svec[j] = dp[j] - e;
    }

    // ---- wave-local suffix composition over all 64 chunks ----
    uint32_t I = rho;
#pragma unroll
    for (int d = 1; d < 64; d <<= 1) {
        uint32_t oth = __shfl_down(I, d);
        uint32_t cm  = mcompose(I, oth);
        I = (c + d < 64) ? cm : I;
    }
    float best = dp[0] + te[0]; int lastv = 0;
#pragma unroll
    for (int j = 1; j < 5; ++j) {
        float s = dp[j] + te[j];
        if (s > best) { best = s; lastv = j; }
    }
    const int last = __shfl(lastv, 63);
    uint32_t M = __shfl_down(I, 1);
    M = (c < 63) ? M : IDENT;
    const int ec = (M >> (3 * last)) & 7;        // class at end of chunk c

    // ---- exact telescoped score: wave reduce ----
    {
        float v = svec[0];
        v = (ec == 1) ? svec[1] : v;
        v = (ec == 2) ? svec[2] : v;
        v = (ec == 3) ? svec[3] : v;
        v = (ec == 4) ? svec[4] : v;
        if (c == 63) v += te[last];
#pragma unroll
        for (int off = 1; off < 64; off <<= 1) v += __shfl_xor(v, off);
        if (c == 0) out[b] = v;
    }

    // ---- path decode from register bp ----
    float pv[32];
    int e = ec;
#pragma unroll
    for (int l = 31; l >= 0; --l) {
        pv[l] = (float)e;
        uint32_t p = (acc[l >> 1] >> (16 * (l & 1))) & 0xFFFFu;
        e = (p >> (3 * e)) & 7;
    }
    float* path = out + B_ + (size_t)b * T_ + c * 32;
#pragma unroll
    for (int q = 0; q < 8; ++q) {
        float4 v; v.x = pv[4*q]; v.y = pv[4*q+1]; v.z = pv[4*q+2]; v.w = pv[4*q+3];
        ((float4*)path)[q] = v;
    }
}

extern "C" void kernel_launch(void* const* d_in, const int* in_sizes, int n_in,
                              void* d_out, int out_size, void* d_ws, size_t ws_size,
                              hipStream_t stream) {
    const float* x         = (const float*)d_in[0];
    const int*   mask      = (const int*)d_in[1];
    const float* transform = (const float*)d_in[2];
    float*       out       = (float*)d_out;

    hipLaunchKernelGGL(k_all, dim3(B_), dim3(64), 0, stream,
                       x, mask, transform, out);
}